// Round 5
// baseline (854.312 us; speedup 1.0000x reference)
//
#include <hip/hip_runtime.h>

#define N_NODES 100000
#define N_EDGES 3200000
#define DIM 128
#define SCAN_BLOCKS 98   // ceil(100000/1024)
#define NPART 8          // one counter partition per XCD (blockIdx & 7)
#define NS 100032        // node stride per partition (100000 -> x64 ints)

// ---------------- helpers ----------------

__device__ __forceinline__ unsigned rne_bf16(float f) {
    unsigned u = __builtin_bit_cast(unsigned, f);
    return (u + 0x7FFFu + ((u >> 16) & 1u)) >> 16;
}
__device__ __forceinline__ float bf16lo(unsigned u) {
    return __builtin_bit_cast(float, u << 16);
}
__device__ __forceinline__ float bf16hi(unsigned u) {
    return __builtin_bit_cast(float, u & 0xFFFF0000u);
}

// ---------------- CSR build (XCD-partitioned rank, single atomic pass) ----------------

// Partition p = blockIdx & 7 matches MI3xx round-robin block->XCD dispatch, so each
// counts8[p] array stays XCD-local: no cross-XCD line ping-pong (round-4 rank_k showed
// WRITE_SIZE 112MB on a 400KB table = coherence migration). Mapping is perf-only;
// correctness holds for any block->XCD assignment.
__global__ __launch_bounds__(256) void rank_k(const int* __restrict__ dst,
                                              int* __restrict__ counts8,
                                              int* __restrict__ rank) {
    int t = blockIdx.x * blockDim.x + threadIdx.x;   // 4 edges per thread
    int* cp = counts8 + (blockIdx.x & (NPART - 1)) * NS;
    int4 d4 = ((const int4*)dst)[t];
    int r0 = atomicAdd(&cp[d4.x], 1);
    int r1 = atomicAdd(&cp[d4.y], 1);
    int r2 = atomicAdd(&cp[d4.z], 1);
    int r3 = atomicAdd(&cp[d4.w], 1);
    ((int4*)rank)[t] = make_int4(r0, r1, r2, r3);
}

// csr[pbase8[p][dst] + rank] = src ; p recomputed from identical grid mapping
__global__ __launch_bounds__(256) void place_k(const int* __restrict__ src,
                                               const int* __restrict__ dst,
                                               const int* __restrict__ rank,
                                               const int* __restrict__ pbase8,
                                               int* __restrict__ csr) {
    int t = blockIdx.x * blockDim.x + threadIdx.x;
    const int* pb = pbase8 + (blockIdx.x & (NPART - 1)) * NS;
    int4 d4 = ((const int4*)dst)[t];
    int4 r4 = ((const int4*)rank)[t];
    int4 s4 = ((const int4*)src)[t];
    int o0 = pb[d4.x];
    int o1 = pb[d4.y];
    int o2 = pb[d4.z];
    int o3 = pb[d4.w];
    __builtin_nontemporal_store(s4.x, &csr[o0 + r4.x]);
    __builtin_nontemporal_store(s4.y, &csr[o1 + r4.y]);
    __builtin_nontemporal_store(s4.z, &csr[o2 + r4.z]);
    __builtin_nontemporal_store(s4.w, &csr[o3 + r4.w]);
}

// scan1 sums the 8 partition counts per node, then block-local exclusive scan
__global__ void scan1_k(const int* __restrict__ counts8, int* __restrict__ offsets,
                        int* __restrict__ blockSums) {
    __shared__ int tmp[256];
    int tid = threadIdx.x;
    int base = blockIdx.x * 1024 + tid * 4;
    int v0 = 0, v1 = 0, v2 = 0, v3 = 0;
#pragma unroll
    for (int p = 0; p < NPART; p++) {
        const int* cp = counts8 + p * NS;
        if (base + 0 < N_NODES) v0 += cp[base + 0];
        if (base + 1 < N_NODES) v1 += cp[base + 1];
        if (base + 2 < N_NODES) v2 += cp[base + 2];
        if (base + 3 < N_NODES) v3 += cp[base + 3];
    }
    int t = v0 + v1 + v2 + v3;
    tmp[tid] = t;
    __syncthreads();
    for (int off = 1; off < 256; off <<= 1) {
        int x = tmp[tid];
        if (tid >= off) x += tmp[tid - off];
        __syncthreads();
        tmp[tid] = x;
        __syncthreads();
    }
    int excl = tmp[tid] - t;
    if (base + 0 < N_NODES) offsets[base + 0] = excl;
    if (base + 1 < N_NODES) offsets[base + 1] = excl + v0;
    if (base + 2 < N_NODES) offsets[base + 2] = excl + v0 + v1;
    if (base + 3 < N_NODES) offsets[base + 3] = excl + v0 + v1 + v2;
    if (tid == 255) blockSums[blockIdx.x] = tmp[255];
}

__global__ void scan2_k(const int* __restrict__ blockSums, int* __restrict__ blockOffsets) {
    __shared__ int tmp[128];
    int tid = threadIdx.x;
    int v = (tid < SCAN_BLOCKS) ? blockSums[tid] : 0;
    tmp[tid] = v;
    __syncthreads();
    for (int off = 1; off < 128; off <<= 1) {
        int x = tmp[tid];
        if (tid >= off) x += tmp[tid - off];
        __syncthreads();
        tmp[tid] = x;
        __syncthreads();
    }
    if (tid < SCAN_BLOCKS) blockOffsets[tid] = tmp[tid] - v;
}

__global__ void scan3_k(int* __restrict__ offsets, const int* __restrict__ blockOffsets) {
    int add = blockOffsets[blockIdx.x];
    int base = blockIdx.x * 1024 + threadIdx.x * 4;
#pragma unroll
    for (int j = 0; j < 4; j++) {
        int i = base + j;
        if (i < N_NODES) offsets[i] += add;
    }
    if (blockIdx.x == 0 && threadIdx.x == 0) offsets[N_NODES] = N_EDGES;
}

// pbase8[p][i] = offsets[i] + sum_{q<p} counts8[q][i]
__global__ __launch_bounds__(256) void pfix_k(const int* __restrict__ counts8,
                                              const int* __restrict__ offsets,
                                              int* __restrict__ pbase8) {
    int i = blockIdx.x * 256 + threadIdx.x;
    if (i >= N_NODES) return;
    int run = offsets[i];
#pragma unroll
    for (int p = 0; p < NPART; p++) {
        pbase8[p * NS + i] = run;
        run += counts8[p * NS + i];
    }
}

// ---------------- per-layer compute ----------------

// G[r][c] = sum_k H[r][k] * W[k][c]; output stored as bf16 (RNE) for the gather
__global__ __launch_bounds__(256) void gemm_k(const float* __restrict__ H,
                                              const float* __restrict__ W,
                                              unsigned short* __restrict__ G) {
    __shared__ float hs[64][128];
    int tid = threadIdx.x;
    int rowBase = blockIdx.x * 64;
    for (int i = tid; i < 64 * 32; i += 256) {
        int r = i >> 5, c4 = i & 31;
        int row = rowBase + r;
        float4 v = make_float4(0.f, 0.f, 0.f, 0.f);
        if (row < N_NODES) v = ((const float4*)(H + (size_t)row * DIM))[c4];
        ((float4*)&hs[r][0])[c4] = v;
    }
    __syncthreads();

    int tx = tid & 31, ty = tid >> 5;
    int c0 = tx * 4, r0 = ty * 8;
    float4 acc[8];
#pragma unroll
    for (int r = 0; r < 8; r++) acc[r] = make_float4(0.f, 0.f, 0.f, 0.f);

#pragma unroll 4
    for (int k = 0; k < DIM; k++) {
        float4 wv = *(const float4*)(W + (size_t)k * DIM + c0);
#pragma unroll
        for (int r = 0; r < 8; r++) {
            float a = hs[r0 + r][k];
            acc[r].x += a * wv.x;
            acc[r].y += a * wv.y;
            acc[r].z += a * wv.z;
            acc[r].w += a * wv.w;
        }
    }
#pragma unroll
    for (int r = 0; r < 8; r++) {
        int row = rowBase + r0 + r;
        if (row < N_NODES) {
            uint2 pk;
            pk.x = rne_bf16(acc[r].x) | (rne_bf16(acc[r].y) << 16);
            pk.y = rne_bf16(acc[r].z) | (rne_bf16(acc[r].w) << 16);
            *(uint2*)(G + (size_t)row * DIM + c0) = pk;
        }
    }
}

// out[i] = (1+eps)*G[i] + sum_{in-edges} G[csr[e]] + b   (G in bf16, out f32)
// One wave per node; pair-gather (2 bf16 rows per uint2 wave-load), 16 edges in flight.
__global__ __launch_bounds__(256) void agg_k(const unsigned short* __restrict__ G,
                                             const int* __restrict__ off,
                                             const int* __restrict__ csr,
                                             const float* __restrict__ bias,
                                             const float* __restrict__ epsp,
                                             float* __restrict__ out) {
    int lane = threadIdx.x & 63;
    int node = blockIdx.x * 4 + (threadIdx.x >> 6);
    int half = lane >> 5;
    int q = lane & 31;
    float e1 = 1.0f + epsp[0];

    float4 acc = make_float4(0.f, 0.f, 0.f, 0.f);
    int s = off[node], e = off[node + 1];
    int n = e - s;
    const int* cl = csr + s;
    int i = 0;
    for (; i + 16 <= n; i += 16) {
        uint2 v[8];
#pragma unroll
        for (int p = 0; p < 8; p++) {
            int idx = cl[i + 2 * p + half];
            v[p] = *(const uint2*)(G + (size_t)idx * DIM + q * 4);
        }
#pragma unroll
        for (int p = 0; p < 8; p++) {
            acc.x += bf16lo(v[p].x);
            acc.y += bf16hi(v[p].x);
            acc.z += bf16lo(v[p].y);
            acc.w += bf16hi(v[p].y);
        }
    }
    for (; i + 2 <= n; i += 2) {
        int idx = cl[i + half];
        uint2 v = *(const uint2*)(G + (size_t)idx * DIM + q * 4);
        acc.x += bf16lo(v.x);
        acc.y += bf16hi(v.x);
        acc.z += bf16lo(v.y);
        acc.w += bf16hi(v.y);
    }
    if (i < n) {
        int idx = cl[n - 1];
        uint2 v = *(const uint2*)(G + (size_t)idx * DIM + q * 4);
        if (half == 0) {
            acc.x += bf16lo(v.x);
            acc.y += bf16hi(v.x);
            acc.z += bf16lo(v.y);
            acc.w += bf16hi(v.y);
        }
    }
    acc.x += __shfl_xor(acc.x, 32);
    acc.y += __shfl_xor(acc.y, 32);
    acc.z += __shfl_xor(acc.z, 32);
    acc.w += __shfl_xor(acc.w, 32);

    if (half == 0) {
        uint2 sv = *(const uint2*)(G + (size_t)node * DIM + q * 4);
        float4 bb = *(const float4*)(bias + q * 4);
        float4 r;
        r.x = acc.x + e1 * bf16lo(sv.x) + bb.x;
        r.y = acc.y + e1 * bf16hi(sv.x) + bb.y;
        r.z = acc.z + e1 * bf16lo(sv.y) + bb.z;
        r.w = acc.w + e1 * bf16hi(sv.y) + bb.w;
        *(float4*)(out + (size_t)node * DIM + q * 4) = r;
    }
}

// ---------------- launch ----------------

extern "C" void kernel_launch(void* const* d_in, const int* in_sizes, int n_in,
                              void* d_out, int out_size, void* d_ws, size_t ws_size,
                              hipStream_t stream) {
    const float* feats = (const float*)d_in[0];
    const int* esrc = (const int*)d_in[1];
    const int* edst = (const int*)d_in[2];
    const float* Wm[3] = {(const float*)d_in[3], (const float*)d_in[6], (const float*)d_in[9]};
    const float* Bv[3] = {(const float*)d_in[4], (const float*)d_in[7], (const float*)d_in[10]};
    const float* Ev[3] = {(const float*)d_in[5], (const float*)d_in[8], (const float*)d_in[11]};
    float* out = (float*)d_out;

    char* ws = (char*)d_ws;
    unsigned short* bufG = (unsigned short*)(ws);     // 25,600,000 B : g = h @ W (bf16)
    int* csr     = (int*)(ws + 25600000);             // 12,800,000 B
    int* rankb   = (int*)(ws + 38400000);             // 12,800,000 B
    int* counts8 = (int*)(ws + 51200000);             //  3,201,024 B (8 x NS)
    int* pbase8  = (int*)(ws + 54401024);             //  3,201,024 B
    int* offsets = (int*)(ws + 57602048);             //    400,004 B
    int* bsums   = (int*)(ws + 58002176);             //        392 B
    int* boffs   = (int*)(ws + 58002688);             //        392 B

    // CSR build: partitioned atomic rank pass, scan, per-partition bases, placement
    hipMemsetAsync(counts8, 0, NPART * NS * sizeof(int), stream);
    rank_k<<<N_EDGES / 1024, 256, 0, stream>>>(edst, counts8, rankb);
    scan1_k<<<SCAN_BLOCKS, 256, 0, stream>>>(counts8, offsets, bsums);
    scan2_k<<<1, 128, 0, stream>>>(bsums, boffs);
    scan3_k<<<SCAN_BLOCKS, 256, 0, stream>>>(offsets, boffs);
    pfix_k<<<(N_NODES + 255) / 256, 256, 0, stream>>>(counts8, offsets, pbase8);
    place_k<<<N_EDGES / 1024, 256, 0, stream>>>(esrc, edst, rankb, pbase8, csr);

    // 3 GIN layers: g = h @ W  (bufG, bf16);  h' = (1+eps)g + agg(g) + b  (d_out, f32)
    const float* h = feats;
    for (int l = 0; l < 3; l++) {
        gemm_k<<<(N_NODES + 63) / 64, 256, 0, stream>>>(h, Wm[l], bufG);
        agg_k<<<N_NODES / 4, 256, 0, stream>>>(bufG, offsets, csr, Bv[l], Ev[l], out);
        h = out;
    }
}

// Round 6
// 727.805 us; speedup vs baseline: 1.1738x; 1.1738x over previous
//
#include <hip/hip_runtime.h>

#define N_NODES 100000
#define N_EDGES 3200000
#define DIM 128
#define NBUCK 391        // ceil(100000/256) buckets of 256 nodes (dst>>8)
#define NBP 392          // padded
#define EB_BLOCKS 782    // ceil(3.2M / 4096) edge blocks (4096 edges/block)

// ---------------- helpers ----------------

__device__ __forceinline__ unsigned rne_bf16(float f) {
    unsigned u = __builtin_bit_cast(unsigned, f);
    return (u + 0x7FFFu + ((u >> 16) & 1u)) >> 16;
}
__device__ __forceinline__ float bf16lo(unsigned u) {
    return __builtin_bit_cast(float, u << 16);
}
__device__ __forceinline__ float bf16hi(unsigned u) {
    return __builtin_bit_cast(float, u & 0xFFFF0000u);
}

// ---------------- CSR build: bucket counting sort ----------------
// Round-5 lesson: device-scope atomics execute at the address's HOME slice
// (memory-side), ~91 atomics/ns wall; XCD-partitioning of counters is useless.
// Fix: cut global atomics 12.8M -> ~0.6M via coarse buckets + LDS ranking.

// B1: per-block LDS hist of 4096 edges into 392 buckets; 1 global atomic per (block,bucket)
__global__ __launch_bounds__(256) void bhist_k(const int* __restrict__ dst,
                                               int* __restrict__ bucketTotal) {
    __shared__ int h[NBP];
    int tid = threadIdx.x;
    for (int i = tid; i < NBP; i += 256) h[i] = 0;
    __syncthreads();
#pragma unroll
    for (int c = 0; c < 4; c++) {
        int e = blockIdx.x * 4096 + c * 1024 + tid * 4;
        if (e < N_EDGES) {
            int4 d4 = ((const int4*)dst)[e >> 2];
            atomicAdd(&h[d4.x >> 8], 1);
            atomicAdd(&h[d4.y >> 8], 1);
            atomicAdd(&h[d4.z >> 8], 1);
            atomicAdd(&h[d4.w >> 8], 1);
        }
    }
    __syncthreads();
    for (int i = tid; i < NBP; i += 256)
        if (h[i] > 0) atomicAdd(&bucketTotal[i], h[i]);
}

// B2: exclusive scan of 392 bucket totals -> bucketBase[0..392], init cursors
__global__ __launch_bounds__(512) void bscan_k(const int* __restrict__ bucketTotal,
                                               int* __restrict__ bucketBase,
                                               int* __restrict__ bucketCursor) {
    __shared__ int tmp[512];
    int tid = threadIdx.x;
    int v = (tid < NBP) ? bucketTotal[tid] : 0;
    tmp[tid] = v;
    __syncthreads();
    for (int off = 1; off < 512; off <<= 1) {
        int x = tmp[tid];
        if (tid >= off) x += tmp[tid - off];
        __syncthreads();
        tmp[tid] = x;
        __syncthreads();
    }
    if (tid < NBP) {
        int excl = tmp[tid] - v;
        bucketBase[tid] = excl;
        bucketCursor[tid] = excl;
        if (tid == NBP - 1) bucketBase[NBP] = tmp[tid];
    }
}

// B3: re-hist per block, reserve per-bucket runs (1 global atomic per block,bucket),
// scatter (src,dst) pairs into bucket regions via LDS cursors
__global__ __launch_bounds__(256) void bscatter_k(const int* __restrict__ src,
                                                  const int* __restrict__ dst,
                                                  int* __restrict__ bucketCursor,
                                                  int2* __restrict__ ebuf) {
    __shared__ int h[NBP];
    __shared__ int lcur[NBP];
    int tid = threadIdx.x;
    for (int i = tid; i < NBP; i += 256) h[i] = 0;
    __syncthreads();
#pragma unroll
    for (int c = 0; c < 4; c++) {
        int e = blockIdx.x * 4096 + c * 1024 + tid * 4;
        if (e < N_EDGES) {
            int4 d4 = ((const int4*)dst)[e >> 2];
            atomicAdd(&h[d4.x >> 8], 1);
            atomicAdd(&h[d4.y >> 8], 1);
            atomicAdd(&h[d4.z >> 8], 1);
            atomicAdd(&h[d4.w >> 8], 1);
        }
    }
    __syncthreads();
    for (int i = tid; i < NBP; i += 256)
        lcur[i] = (h[i] > 0) ? atomicAdd(&bucketCursor[i], h[i]) : 0;
    __syncthreads();
#pragma unroll
    for (int c = 0; c < 4; c++) {
        int e = blockIdx.x * 4096 + c * 1024 + tid * 4;
        if (e < N_EDGES) {
            int4 d4 = ((const int4*)dst)[e >> 2];
            int4 s4 = ((const int4*)src)[e >> 2];
            int p0 = atomicAdd(&lcur[d4.x >> 8], 1);
            int p1 = atomicAdd(&lcur[d4.y >> 8], 1);
            int p2 = atomicAdd(&lcur[d4.z >> 8], 1);
            int p3 = atomicAdd(&lcur[d4.w >> 8], 1);
            ebuf[p0] = make_int2(s4.x, d4.x);
            ebuf[p1] = make_int2(s4.y, d4.y);
            ebuf[p2] = make_int2(s4.z, d4.z);
            ebuf[p3] = make_int2(s4.w, d4.w);
        }
    }
}

// B4: one block per bucket (256 nodes, ~8.2K edges): LDS count, scan -> offsets,
// LDS-cursor rank -> final csr. Zero global atomics.
__global__ __launch_bounds__(256) void bfinal_k(const int2* __restrict__ ebuf,
                                                const int* __restrict__ bucketBase,
                                                int* __restrict__ offsets,
                                                int* __restrict__ csr) {
    __shared__ int h[256];
    __shared__ int sc[256];
    int tid = threadIdx.x;
    int b = blockIdx.x;
    int s = bucketBase[b], e = bucketBase[b + 1];
    h[tid] = 0;
    __syncthreads();
    for (int idx = s + tid; idx < e; idx += 256) {
        int2 ed = ebuf[idx];
        atomicAdd(&h[ed.y & 255], 1);
    }
    __syncthreads();
    sc[tid] = h[tid];
    __syncthreads();
    for (int off = 1; off < 256; off <<= 1) {
        int x = sc[tid];
        if (tid >= off) x += sc[tid - off];
        __syncthreads();
        sc[tid] = x;
        __syncthreads();
    }
    int excl = sc[tid] - h[tid];
    int node = b * 256 + tid;
    if (node < N_NODES) offsets[node] = s + excl;
    if (b == 0 && tid == 0) offsets[N_NODES] = N_EDGES;
    __syncthreads();
    h[tid] = s + excl;   // reuse as cursor
    __syncthreads();
    for (int idx = s + tid; idx < e; idx += 256) {
        int2 ed = ebuf[idx];
        int pos = atomicAdd(&h[ed.y & 255], 1);
        csr[pos] = ed.x;
    }
}

// ---------------- per-layer compute ----------------

// G[r][c] = sum_k H[r][k] * W[k][c]; output stored as bf16 (RNE) for the gather
__global__ __launch_bounds__(256) void gemm_k(const float* __restrict__ H,
                                              const float* __restrict__ W,
                                              unsigned short* __restrict__ G) {
    __shared__ float hs[64][128];
    int tid = threadIdx.x;
    int rowBase = blockIdx.x * 64;
    for (int i = tid; i < 64 * 32; i += 256) {
        int r = i >> 5, c4 = i & 31;
        int row = rowBase + r;
        float4 v = make_float4(0.f, 0.f, 0.f, 0.f);
        if (row < N_NODES) v = ((const float4*)(H + (size_t)row * DIM))[c4];
        ((float4*)&hs[r][0])[c4] = v;
    }
    __syncthreads();

    int tx = tid & 31, ty = tid >> 5;
    int c0 = tx * 4, r0 = ty * 8;
    float4 acc[8];
#pragma unroll
    for (int r = 0; r < 8; r++) acc[r] = make_float4(0.f, 0.f, 0.f, 0.f);

#pragma unroll 4
    for (int k = 0; k < DIM; k++) {
        float4 wv = *(const float4*)(W + (size_t)k * DIM + c0);
#pragma unroll
        for (int r = 0; r < 8; r++) {
            float a = hs[r0 + r][k];
            acc[r].x += a * wv.x;
            acc[r].y += a * wv.y;
            acc[r].z += a * wv.z;
            acc[r].w += a * wv.w;
        }
    }
#pragma unroll
    for (int r = 0; r < 8; r++) {
        int row = rowBase + r0 + r;
        if (row < N_NODES) {
            uint2 pk;
            pk.x = rne_bf16(acc[r].x) | (rne_bf16(acc[r].y) << 16);
            pk.y = rne_bf16(acc[r].z) | (rne_bf16(acc[r].w) << 16);
            *(uint2*)(G + (size_t)row * DIM + c0) = pk;
        }
    }
}

template <int P>
__device__ __forceinline__ void gather_pairs(const unsigned short* __restrict__ G,
                                             const int* __restrict__ cl, int i,
                                             int half, int q, float4& acc) {
    uint2 v[P];
#pragma unroll
    for (int p = 0; p < P; p++) {
        int idx = cl[i + 2 * p + half];
        v[p] = *(const uint2*)(G + (size_t)idx * DIM + q * 4);
    }
#pragma unroll
    for (int p = 0; p < P; p++) {
        acc.x += bf16lo(v[p].x);
        acc.y += bf16hi(v[p].x);
        acc.z += bf16lo(v[p].y);
        acc.w += bf16hi(v[p].y);
    }
}

// out[i] = (1+eps)*G[i] + sum_{in-edges} G[csr[e]] + b   (G bf16, out f32)
// One wave/node; pair-gather (2 bf16 rows per uint2 wave-load); 32 edges in
// flight in main loop; hierarchical 16/8/4/2/1 tail (avg degree 32).
__global__ __launch_bounds__(256) void agg_k(const unsigned short* __restrict__ G,
                                             const int* __restrict__ off,
                                             const int* __restrict__ csr,
                                             const float* __restrict__ bias,
                                             const float* __restrict__ epsp,
                                             float* __restrict__ out) {
    int lane = threadIdx.x & 63;
    int node = blockIdx.x * 4 + (threadIdx.x >> 6);
    int half = lane >> 5;
    int q = lane & 31;
    float e1 = 1.0f + epsp[0];

    float4 acc = make_float4(0.f, 0.f, 0.f, 0.f);
    int s = off[node], e = off[node + 1];
    int n = e - s;
    const int* cl = csr + s;
    int i = 0;
    for (; i + 32 <= n; i += 32) gather_pairs<16>(G, cl, i, half, q, acc);
    if (i + 16 <= n) { gather_pairs<8>(G, cl, i, half, q, acc); i += 16; }
    if (i + 8 <= n)  { gather_pairs<4>(G, cl, i, half, q, acc); i += 8; }
    if (i + 4 <= n)  { gather_pairs<2>(G, cl, i, half, q, acc); i += 4; }
    if (i + 2 <= n)  { gather_pairs<1>(G, cl, i, half, q, acc); i += 2; }
    if (i < n) {  // odd tail: both halves load same row, only half A accumulates
        int idx = cl[n - 1];
        uint2 v = *(const uint2*)(G + (size_t)idx * DIM + q * 4);
        if (half == 0) {
            acc.x += bf16lo(v.x);
            acc.y += bf16hi(v.x);
            acc.z += bf16lo(v.y);
            acc.w += bf16hi(v.y);
        }
    }
    acc.x += __shfl_xor(acc.x, 32);
    acc.y += __shfl_xor(acc.y, 32);
    acc.z += __shfl_xor(acc.z, 32);
    acc.w += __shfl_xor(acc.w, 32);

    if (half == 0) {
        uint2 sv = *(const uint2*)(G + (size_t)node * DIM + q * 4);
        float4 bb = *(const float4*)(bias + q * 4);
        float4 r;
        r.x = acc.x + e1 * bf16lo(sv.x) + bb.x;
        r.y = acc.y + e1 * bf16hi(sv.x) + bb.y;
        r.z = acc.z + e1 * bf16lo(sv.y) + bb.z;
        r.w = acc.w + e1 * bf16hi(sv.y) + bb.w;
        *(float4*)(out + (size_t)node * DIM + q * 4) = r;
    }
}

// ---------------- launch ----------------

extern "C" void kernel_launch(void* const* d_in, const int* in_sizes, int n_in,
                              void* d_out, int out_size, void* d_ws, size_t ws_size,
                              hipStream_t stream) {
    const float* feats = (const float*)d_in[0];
    const int* esrc = (const int*)d_in[1];
    const int* edst = (const int*)d_in[2];
    const float* Wm[3] = {(const float*)d_in[3], (const float*)d_in[6], (const float*)d_in[9]};
    const float* Bv[3] = {(const float*)d_in[4], (const float*)d_in[7], (const float*)d_in[10]};
    const float* Ev[3] = {(const float*)d_in[5], (const float*)d_in[8], (const float*)d_in[11]};
    float* out = (float*)d_out;

    char* ws = (char*)d_ws;
    unsigned short* bufG = (unsigned short*)(ws);     // 25,600,000 B : g = h @ W (bf16)
    int* csr        = (int*)(ws + 25600000);          // 12,800,000 B
    int2* ebuf      = (int2*)(ws + 38400000);         // 25,600,000 B (src,dst) bucketed
    int* offsets    = (int*)(ws + 64000000);          //    400,004 B
    int* bucketTotal= (int*)(ws + 64400128);          //      1,568 B
    int* bucketBase = (int*)(ws + 64401792);          //      1,572 B
    int* bucketCur  = (int*)(ws + 64403456);          //      1,568 B

    // CSR build: bucket counting sort (global atomics ~0.6M vs 12.8M)
    hipMemsetAsync(bucketTotal, 0, NBP * sizeof(int), stream);
    bhist_k<<<EB_BLOCKS, 256, 0, stream>>>(edst, bucketTotal);
    bscan_k<<<1, 512, 0, stream>>>(bucketTotal, bucketBase, bucketCur);
    bscatter_k<<<EB_BLOCKS, 256, 0, stream>>>(esrc, edst, bucketCur, ebuf);
    bfinal_k<<<NBUCK, 256, 0, stream>>>(ebuf, bucketBase, offsets, csr);

    // 3 GIN layers: g = h @ W  (bufG, bf16);  h' = (1+eps)g + agg(g) + b  (d_out, f32)
    const float* h = feats;
    for (int l = 0; l < 3; l++) {
        gemm_k<<<(N_NODES + 63) / 64, 256, 0, stream>>>(h, Wm[l], bufG);
        agg_k<<<N_NODES / 4, 256, 0, stream>>>(bufG, offsets, csr, Bv[l], Ev[l], out);
        h = out;
    }
}